// Round 8
// baseline (570.228 us; speedup 1.0000x reference)
//
#include <hip/hip_runtime.h>

#define F 128
#define RELS 8
#define KMAX 64
#define NT 16  // nodes per fused block (Zf = 16*8*128*4B = 64KB -> 2 blocks/CU, 512 thr)

typedef __attribute__((ext_vector_type(8))) short short8;
typedef __attribute__((ext_vector_type(4))) float floatx4;

__device__ __forceinline__ unsigned short f2bf(float f) {
    unsigned int u = __float_as_uint(f);
    unsigned int r = (u + 0x7fffu + ((u >> 16) & 1u)) >> 16;
    return (unsigned short)r;
}

#define LOF(v) __uint_as_float((v) << 16)
#define HIF(v) __uint_as_float((v) & 0xffff0000u)

// ---------- prep: fillp (padded CSR) + cvtX + cvtW in ONE dispatch ----------
__global__ __launch_bounds__(256) void prep_kernel(const float* __restrict__ X, const float* __restrict__ W,
                                                   const int* __restrict__ src, const int* __restrict__ dst,
                                                   const int* __restrict__ et,
                                                   unsigned short* __restrict__ X2, unsigned short* __restrict__ W2,
                                                   int* __restrict__ counts, unsigned int* __restrict__ packed,
                                                   int E, int N, int BF, int BX) {
    int bid = blockIdx.x;
    int tid = threadIdx.x;
    if (bid < BF) {
        // fill padded CSR
        int t = bid * 256 + tid;
        if (t < E) {
            int d = dst[t];
            int slot = atomicAdd(&counts[d], 1);
            if (slot < KMAX)
                packed[(size_t)d * KMAX + slot] = (unsigned int)src[t] | ((unsigned int)et[t] << 24);
        }
    } else if (bid < BF + BX) {
        // X fp32 -> X2 [N][128] bf16
        int t = (bid - BF) * 256 + tid;
        if (t < N * (F / 8)) {
            int n = t >> 4;
            int fi = (t & 15) * 8;
            const float* xp = X + (size_t)n * F + fi;
            float4 v0 = *reinterpret_cast<const float4*>(xp);
            float4 v1 = *reinterpret_cast<const float4*>(xp + 4);
            short8 o;
            o[0] = (short)f2bf(v0.x); o[1] = (short)f2bf(v0.y);
            o[2] = (short)f2bf(v0.z); o[3] = (short)f2bf(v0.w);
            o[4] = (short)f2bf(v1.x); o[5] = (short)f2bf(v1.y);
            o[6] = (short)f2bf(v1.z); o[7] = (short)f2bf(v1.w);
            *reinterpret_cast<short8*>(X2 + (size_t)n * F + fi) = o;
        }
    } else {
        // W fp32 -> W2 [r][kc][fo][32] bf16
        int t = (bid - BF - BX) * 256 + tid;
        if (t < RELS * F * (F / 8)) {
            int r = t >> 11;
            int rem = t & 2047;
            int fo = rem >> 4;
            int fi = (rem & 15) * 8;
            const float* wp = W + ((size_t)r * F + fo) * F + fi;
            float4 v0 = *reinterpret_cast<const float4*>(wp);
            float4 v1 = *reinterpret_cast<const float4*>(wp + 4);
            int kc = fi >> 5;
            int ko = fi & 31;
            short8 o;
            o[0] = (short)f2bf(v0.x); o[1] = (short)f2bf(v0.y);
            o[2] = (short)f2bf(v0.z); o[3] = (short)f2bf(v0.w);
            o[4] = (short)f2bf(v1.x); o[5] = (short)f2bf(v1.y);
            o[6] = (short)f2bf(v1.z); o[7] = (short)f2bf(v1.w);
            *reinterpret_cast<short8*>(W2 + ((size_t)((r * 4 + kc) * F + fo)) * 32 + ko) = o;
        }
    }
}

// ---------- fused aggregate (LDS fp32 atomics, branch-free) + transform (MFMA) ----------
// Zf[nl][rel][128] f32 in LDS. Swizzle: f32-elem k of row (nl) stored at k ^ ((nl&7)<<2).
// Phase 1: wave w owns nodes w*2, w*2+1. Per edge: one coalesced 256B X2-row read
//          (lane l -> feature pair 2l,2l+1), 2x ds_add_f32 at rel-indexed address.
//          No branches, no accumulator chain: only the index load is serial.
// Phase 2: wave w computes col-tile w (16 cols): A-frag read from Zf as f32
//          (2x b128, swizzled, bank-balanced), cvt_pk to bf16, 8 rels x 4 kc MFMA.
__global__ __launch_bounds__(512) void fused_kernel(const unsigned int* __restrict__ X2u,
                                                    const unsigned short* __restrict__ W2,
                                                    const int* __restrict__ counts,
                                                    const unsigned int* __restrict__ packed,
                                                    float* __restrict__ Y, int N) {
    __shared__ float Zf[NT * RELS * F];  // 64 KB
    int tid = threadIdx.x;
    int lane = tid & 63;
    int wave = tid >> 6;
    int nodebase = blockIdx.x * NT;

    // zero Zf: 16384 floats = 4096 float4 over 512 threads
    float4* zp = reinterpret_cast<float4*>(Zf);
#pragma unroll
    for (int i = 0; i < 8; i++) zp[i * 512 + tid] = make_float4(0.f, 0.f, 0.f, 0.f);
    __syncthreads();

    // ---- phase 1 ----
    int k0 = 2 * lane;
#pragma unroll 1
    for (int i = 0; i < 2; i++) {
        int nl = wave * 2 + i;
        int node = nodebase + nl;
        if (node < N) {
            int cnt = counts[node];
            if (cnt > KMAX) cnt = KMAX;
            const unsigned int* pk = packed + (size_t)node * KMAX;
            int sw = (nl & 7) << 2;
            int i0 = k0 ^ sw;
            int i1 = (k0 + 1) ^ sw;
            float* zrow = Zf + (size_t)nl * (RELS * F);
            int nq = cnt >> 2;
            int rem = cnt & 3;
            if (nq) {
                uint4 p = *reinterpret_cast<const uint4*>(pk);
#pragma unroll 1
                for (int qi = 1; qi < nq; qi++) {
                    uint4 pn = *reinterpret_cast<const uint4*>(pk + qi * 4);
                    unsigned int v0 = X2u[(size_t)(p.x & 0xffffffu) * 64 + lane];
                    unsigned int v1 = X2u[(size_t)(p.y & 0xffffffu) * 64 + lane];
                    unsigned int v2 = X2u[(size_t)(p.z & 0xffffffu) * 64 + lane];
                    unsigned int v3 = X2u[(size_t)(p.w & 0xffffffu) * 64 + lane];
                    float* z0 = zrow + (p.x >> 24) * F;
                    atomicAdd(z0 + i0, LOF(v0)); atomicAdd(z0 + i1, HIF(v0));
                    float* z1 = zrow + (p.y >> 24) * F;
                    atomicAdd(z1 + i0, LOF(v1)); atomicAdd(z1 + i1, HIF(v1));
                    float* z2 = zrow + (p.z >> 24) * F;
                    atomicAdd(z2 + i0, LOF(v2)); atomicAdd(z2 + i1, HIF(v2));
                    float* z3 = zrow + (p.w >> 24) * F;
                    atomicAdd(z3 + i0, LOF(v3)); atomicAdd(z3 + i1, HIF(v3));
                    p = pn;
                }
                unsigned int v0 = X2u[(size_t)(p.x & 0xffffffu) * 64 + lane];
                unsigned int v1 = X2u[(size_t)(p.y & 0xffffffu) * 64 + lane];
                unsigned int v2 = X2u[(size_t)(p.z & 0xffffffu) * 64 + lane];
                unsigned int v3 = X2u[(size_t)(p.w & 0xffffffu) * 64 + lane];
                float* z0 = zrow + (p.x >> 24) * F;
                atomicAdd(z0 + i0, LOF(v0)); atomicAdd(z0 + i1, HIF(v0));
                float* z1 = zrow + (p.y >> 24) * F;
                atomicAdd(z1 + i0, LOF(v1)); atomicAdd(z1 + i1, HIF(v1));
                float* z2 = zrow + (p.z >> 24) * F;
                atomicAdd(z2 + i0, LOF(v2)); atomicAdd(z2 + i1, HIF(v2));
                float* z3 = zrow + (p.w >> 24) * F;
                atomicAdd(z3 + i0, LOF(v3)); atomicAdd(z3 + i1, HIF(v3));
            }
            const unsigned int* tail = pk + nq * 4;
            for (int t = 0; t < rem; t++) {
                unsigned int p = tail[t];
                unsigned int v = X2u[(size_t)(p & 0xffffffu) * 64 + lane];
                float* z = zrow + (p >> 24) * F;
                atomicAdd(z + i0, LOF(v)); atomicAdd(z + i1, HIF(v));
            }
        }
    }
    __syncthreads();

    // ---- phase 2: wave w = col-tile w ----
    int lr = lane & 15;
    int hi = lane >> 4;
    int sw = (lr & 7) << 2;  // A-row = lr -> same swizzle as writes to that row
    const float* zrow = Zf + (size_t)lr * (RELS * F);
    floatx4 acc = {0.f, 0.f, 0.f, 0.f};
#pragma unroll
    for (int r = 0; r < RELS; r++) {
#pragma unroll
        for (int kc = 0; kc < 4; kc++) {
            int kbase = kc * 32 + hi * 8;
            float4 f0 = *reinterpret_cast<const float4*>(zrow + r * F + (kbase ^ sw));
            float4 f1 = *reinterpret_cast<const float4*>(zrow + r * F + ((kbase + 4) ^ sw));
            uint4 uu;
            asm("v_cvt_pk_bf16_f32 %0, %1, %2" : "=v"(uu.x) : "v"(f0.x), "v"(f0.y));
            asm("v_cvt_pk_bf16_f32 %0, %1, %2" : "=v"(uu.y) : "v"(f0.z), "v"(f0.w));
            asm("v_cvt_pk_bf16_f32 %0, %1, %2" : "=v"(uu.z) : "v"(f1.x), "v"(f1.y));
            asm("v_cvt_pk_bf16_f32 %0, %1, %2" : "=v"(uu.w) : "v"(f1.z), "v"(f1.w));
            short8 av = *reinterpret_cast<short8*>(&uu);
            short8 b = *reinterpret_cast<const short8*>(W2 + ((size_t)((r * 4 + kc) * F + wave * 16 + lr)) * 32 + hi * 8);
            acc = __builtin_amdgcn_mfma_f32_16x16x32_bf16(av, b, acc, 0, 0, 0);
        }
    }

    // ---- epilogue: C/D col=lane&15, row=(lane>>4)*4+g ----
    int col = wave * 16 + lr;
#pragma unroll
    for (int g = 0; g < 4; g++) {
        int row = nodebase + hi * 4 + g;
        if (row < N) Y[(size_t)row * F + col] = acc[g];
    }
}

// ---------- fallback: fused per-edge fp32 GEMV (used only if ws too small) ----------
__global__ void fused_fb_kernel(const float* __restrict__ X, const float* __restrict__ W,
                                const int* __restrict__ src, const int* __restrict__ dst,
                                const int* __restrict__ et, float* __restrict__ Y, int E) {
    int lane = threadIdx.x & 63;
    int wid = (blockIdx.x * blockDim.x + threadIdx.x) >> 6;
    int nw = (gridDim.x * blockDim.x) >> 6;
    for (int e = wid; e < E; e += nw) {
        int s = src[e];
        int d = dst[e];
        int r = et[e];
        const float4* xr = reinterpret_cast<const float4*>(X + (size_t)s * F);
#pragma unroll
        for (int h = 0; h < 2; h++) {
            int fo = lane + (h << 6);
            const float4* wr = reinterpret_cast<const float4*>(W + ((size_t)r * F + fo) * F);
            float acc = 0.f;
#pragma unroll
            for (int i = 0; i < 32; i++) {
                float4 x = xr[i];
                float4 w = wr[i];
                acc += x.x * w.x + x.y * w.y + x.z * w.z + x.w * w.w;
            }
            unsafeAtomicAdd(&Y[(size_t)d * F + fo], acc);
        }
    }
}

extern "C" void kernel_launch(void* const* d_in, const int* in_sizes, int n_in,
                              void* d_out, int out_size, void* d_ws, size_t ws_size,
                              hipStream_t stream) {
    const float* X = (const float*)d_in[0];
    const float* W = (const float*)d_in[1];
    const int* src = (const int*)d_in[2];
    const int* dst = (const int*)d_in[3];
    const int* et  = (const int*)d_in[4];
    int N = in_sizes[0] / F;
    int E = in_sizes[2];
    float* Y = (float*)d_out;

    size_t x2bytes  = (size_t)N * F * 2;
    size_t w2bytes  = (size_t)RELS * F * F * 2;
    size_t cntbytes = ((size_t)N * 4 + 255) & ~255ull;
    size_t pkbytes  = (size_t)N * KMAX * 4;
    size_t need = x2bytes + w2bytes + cntbytes + pkbytes;

    if (ws_size < need) {
        hipMemsetAsync(d_out, 0, (size_t)N * F * sizeof(float), stream);
        fused_fb_kernel<<<2048, 256, 0, stream>>>(X, W, src, dst, et, Y, E);
        return;
    }

    char* ws = (char*)d_ws;
    unsigned short* X2 = (unsigned short*)ws;  ws += x2bytes;
    unsigned short* W2 = (unsigned short*)ws;  ws += w2bytes;
    int* counts        = (int*)ws;             ws += cntbytes;
    unsigned int* packed = (unsigned int*)ws;

    int BF = (E + 255) / 256;
    int BX = (N * (F / 8) + 255) / 256;
    int BW = (RELS * F * (F / 8) + 255) / 256;

    hipMemsetAsync(counts, 0, (size_t)N * 4, stream);
    prep_kernel<<<BF + BX + BW, 256, 0, stream>>>(X, W, src, dst, et, X2, W2, counts, packed, E, N, BF, BX);
    fused_kernel<<<(N + NT - 1) / NT, 512, 0, stream>>>((const unsigned int*)X2, W2, counts, packed, Y, N);
}

// Round 9
// 210.949 us; speedup vs baseline: 2.7031x; 2.7031x over previous
//
#include <hip/hip_runtime.h>

#define F 128
#define RELS 8
#define KMAX 64
#define NT 16  // nodes per fused block; Zl = 8*16*64*4B = 32KB

typedef __attribute__((ext_vector_type(8))) short short8;
typedef __attribute__((ext_vector_type(4))) float floatx4;

__device__ __forceinline__ unsigned short f2bf(float f) {
    unsigned int u = __float_as_uint(f);
    unsigned int r = (u + 0x7fffu + ((u >> 16) & 1u)) >> 16;
    return (unsigned short)r;
}

#define LOF(v) __uint_as_float((v) << 16)
#define HIF(v) __uint_as_float((v) & 0xffff0000u)

// branch-free predicated accumulate: pure cndmask+add, keeps loads in flight
#define ACCP(rr, vv)                                                       \
    {                                                                      \
        unsigned int _r = (rr);                                            \
        float _lx = LOF(vv), _ly = HIF(vv);                                \
        a0x += (_r == 0) ? _lx : 0.f; a0y += (_r == 0) ? _ly : 0.f;        \
        a1x += (_r == 1) ? _lx : 0.f; a1y += (_r == 1) ? _ly : 0.f;        \
        a2x += (_r == 2) ? _lx : 0.f; a2y += (_r == 2) ? _ly : 0.f;        \
        a3x += (_r == 3) ? _lx : 0.f; a3y += (_r == 3) ? _ly : 0.f;        \
        a4x += (_r == 4) ? _lx : 0.f; a4y += (_r == 4) ? _ly : 0.f;        \
        a5x += (_r == 5) ? _lx : 0.f; a5y += (_r == 5) ? _ly : 0.f;        \
        a6x += (_r == 6) ? _lx : 0.f; a6y += (_r == 6) ? _ly : 0.f;        \
        a7x += (_r == 7) ? _lx : 0.f; a7y += (_r == 7) ? _ly : 0.f;        \
    }

// ---------- prep: fillp (padded CSR) + cvtX + cvtW in ONE dispatch ----------
__global__ __launch_bounds__(256) void prep_kernel(const float* __restrict__ X, const float* __restrict__ W,
                                                   const int* __restrict__ src, const int* __restrict__ dst,
                                                   const int* __restrict__ et,
                                                   unsigned short* __restrict__ X2, unsigned short* __restrict__ W2,
                                                   int* __restrict__ counts, unsigned int* __restrict__ packed,
                                                   int E, int N, int BF, int BX) {
    int bid = blockIdx.x;
    int tid = threadIdx.x;
    if (bid < BF) {
        int t = bid * 256 + tid;
        if (t < E) {
            int d = dst[t];
            int slot = atomicAdd(&counts[d], 1);
            if (slot < KMAX)
                packed[(size_t)d * KMAX + slot] = (unsigned int)src[t] | ((unsigned int)et[t] << 24);
        }
    } else if (bid < BF + BX) {
        int t = (bid - BF) * 256 + tid;
        if (t < N * (F / 8)) {
            int n = t >> 4;
            int fi = (t & 15) * 8;
            const float* xp = X + (size_t)n * F + fi;
            float4 v0 = *reinterpret_cast<const float4*>(xp);
            float4 v1 = *reinterpret_cast<const float4*>(xp + 4);
            short8 o;
            o[0] = (short)f2bf(v0.x); o[1] = (short)f2bf(v0.y);
            o[2] = (short)f2bf(v0.z); o[3] = (short)f2bf(v0.w);
            o[4] = (short)f2bf(v1.x); o[5] = (short)f2bf(v1.y);
            o[6] = (short)f2bf(v1.z); o[7] = (short)f2bf(v1.w);
            *reinterpret_cast<short8*>(X2 + (size_t)n * F + fi) = o;
        }
    } else {
        int t = (bid - BF - BX) * 256 + tid;
        if (t < RELS * F * (F / 8)) {
            int r = t >> 11;
            int rem = t & 2047;
            int fo = rem >> 4;
            int fi = (rem & 15) * 8;
            const float* wp = W + ((size_t)r * F + fo) * F + fi;
            float4 v0 = *reinterpret_cast<const float4*>(wp);
            float4 v1 = *reinterpret_cast<const float4*>(wp + 4);
            int kc = fi >> 5;
            int ko = fi & 31;
            short8 o;
            o[0] = (short)f2bf(v0.x); o[1] = (short)f2bf(v0.y);
            o[2] = (short)f2bf(v0.z); o[3] = (short)f2bf(v0.w);
            o[4] = (short)f2bf(v1.x); o[5] = (short)f2bf(v1.y);
            o[6] = (short)f2bf(v1.z); o[7] = (short)f2bf(v1.w);
            *reinterpret_cast<short8*>(W2 + ((size_t)((r * 4 + kc) * F + fo)) * 32 + ko) = o;
        }
    }
}

// ---------- fused aggregate (branch-free reg accum) + transform (MFMA) ----------
// Phase 1: wave w owns nodes w*4..w*4+3; per edge one coalesced 256B X2-row read
//          (lane l holds feature pair 2l,2l+1); predicated per-rel fp32 accum;
//          bf16-pack to LDS Z[r][nl][128] with XOR swizzle.
// Phase 2: Y_tile(16n x 128) = sum_r Z[r] @ W2[r]^T via mfma 16x16x32;
//          wave w computes col-tiles {2w, 2w+1}.
__global__ __launch_bounds__(256) void fused_kernel(const unsigned int* __restrict__ X2u,
                                                    const unsigned short* __restrict__ W2,
                                                    const int* __restrict__ counts,
                                                    const unsigned int* __restrict__ packed,
                                                    float* __restrict__ Y, int N) {
    __shared__ unsigned int Zl[RELS * NT * 64];  // 32 KB
    int lane = threadIdx.x & 63;
    int wave = threadIdx.x >> 6;
    int nodebase = blockIdx.x * NT;

    // ---- phase 1 ----
#pragma unroll 1
    for (int i = 0; i < NT / 4; i++) {
        int nl = wave * (NT / 4) + i;
        int node = nodebase + nl;
        float a0x = 0, a0y = 0, a1x = 0, a1y = 0, a2x = 0, a2y = 0, a3x = 0, a3y = 0;
        float a4x = 0, a4y = 0, a5x = 0, a5y = 0, a6x = 0, a6y = 0, a7x = 0, a7y = 0;
        if (node < N) {
            int cnt = counts[node];
            if (cnt > KMAX) cnt = KMAX;
            const unsigned int* pk = packed + (size_t)node * KMAX;
            int nq = cnt >> 2;
            int rem = cnt & 3;
            if (nq) {
                uint4 p = *reinterpret_cast<const uint4*>(pk);
#pragma unroll 1
                for (int qi = 1; qi < nq; qi++) {
                    uint4 pn = *reinterpret_cast<const uint4*>(pk + qi * 4);
                    unsigned int v0 = X2u[(size_t)(p.x & 0xffffffu) * 64 + lane];
                    unsigned int v1 = X2u[(size_t)(p.y & 0xffffffu) * 64 + lane];
                    unsigned int v2 = X2u[(size_t)(p.z & 0xffffffu) * 64 + lane];
                    unsigned int v3 = X2u[(size_t)(p.w & 0xffffffu) * 64 + lane];
                    ACCP(p.x >> 24, v0);
                    ACCP(p.y >> 24, v1);
                    ACCP(p.z >> 24, v2);
                    ACCP(p.w >> 24, v3);
                    p = pn;
                }
                unsigned int v0 = X2u[(size_t)(p.x & 0xffffffu) * 64 + lane];
                unsigned int v1 = X2u[(size_t)(p.y & 0xffffffu) * 64 + lane];
                unsigned int v2 = X2u[(size_t)(p.z & 0xffffffu) * 64 + lane];
                unsigned int v3 = X2u[(size_t)(p.w & 0xffffffu) * 64 + lane];
                ACCP(p.x >> 24, v0);
                ACCP(p.y >> 24, v1);
                ACCP(p.z >> 24, v2);
                ACCP(p.w >> 24, v3);
            }
            const unsigned int* tail = pk + nq * 4;
            for (int t = 0; t < rem; t++) {
                unsigned int p = tail[t];
                unsigned int v = X2u[(size_t)(p & 0xffffffu) * 64 + lane];
                ACCP(p >> 24, v);
            }
        }
        int sl = lane ^ ((nl & 7) << 2);  // XOR-swizzle uint slot
        Zl[(0 * NT + nl) * 64 + sl] = (unsigned int)f2bf(a0x) | ((unsigned int)f2bf(a0y) << 16);
        Zl[(1 * NT + nl) * 64 + sl] = (unsigned int)f2bf(a1x) | ((unsigned int)f2bf(a1y) << 16);
        Zl[(2 * NT + nl) * 64 + sl] = (unsigned int)f2bf(a2x) | ((unsigned int)f2bf(a2y) << 16);
        Zl[(3 * NT + nl) * 64 + sl] = (unsigned int)f2bf(a3x) | ((unsigned int)f2bf(a3y) << 16);
        Zl[(4 * NT + nl) * 64 + sl] = (unsigned int)f2bf(a4x) | ((unsigned int)f2bf(a4y) << 16);
        Zl[(5 * NT + nl) * 64 + sl] = (unsigned int)f2bf(a5x) | ((unsigned int)f2bf(a5y) << 16);
        Zl[(6 * NT + nl) * 64 + sl] = (unsigned int)f2bf(a6x) | ((unsigned int)f2bf(a6y) << 16);
        Zl[(7 * NT + nl) * 64 + sl] = (unsigned int)f2bf(a7x) | ((unsigned int)f2bf(a7y) << 16);
    }
    __syncthreads();

    // ---- phase 2: one 16-row tile, wave w does col-tiles {2w, 2w+1} ----
    int lr = lane & 15;
    int hi = lane >> 4;
    int lk8 = hi * 8;
    int nl0 = lr;
    floatx4 acc00 = {0, 0, 0, 0}, acc01 = {0, 0, 0, 0};
#pragma unroll
    for (int r = 0; r < RELS; r++) {
#pragma unroll
        for (int kc = 0; kc < 4; kc++) {
            int ks = kc * 16 + hi * 4;
            short8 av = *reinterpret_cast<const short8*>(&Zl[(r * NT + nl0) * 64 + (ks ^ ((nl0 & 7) << 2))]);
            short8 b0 = *reinterpret_cast<const short8*>(W2 + ((size_t)((r * 4 + kc) * F + (wave * 2) * 16 + lr)) * 32 + lk8);
            short8 b1 = *reinterpret_cast<const short8*>(W2 + ((size_t)((r * 4 + kc) * F + (wave * 2 + 1) * 16 + lr)) * 32 + lk8);
            acc00 = __builtin_amdgcn_mfma_f32_16x16x32_bf16(av, b0, acc00, 0, 0, 0);
            acc01 = __builtin_amdgcn_mfma_f32_16x16x32_bf16(av, b1, acc01, 0, 0, 0);
        }
    }

    // ---- epilogue: C/D layout col=lane&15, row=(lane>>4)*4+g ----
    int c0 = (wave * 2) * 16 + lr;
    int c1 = (wave * 2 + 1) * 16 + lr;
#pragma unroll
    for (int g = 0; g < 4; g++) {
        int row = nodebase + hi * 4 + g;
        if (row < N) {
            Y[(size_t)row * F + c0] = acc00[g];
            Y[(size_t)row * F + c1] = acc01[g];
        }
    }
}

// ---------- fallback: fused per-edge fp32 GEMV (used only if ws too small) ----------
__global__ void fused_fb_kernel(const float* __restrict__ X, const float* __restrict__ W,
                                const int* __restrict__ src, const int* __restrict__ dst,
                                const int* __restrict__ et, float* __restrict__ Y, int E) {
    int lane = threadIdx.x & 63;
    int wid = (blockIdx.x * blockDim.x + threadIdx.x) >> 6;
    int nw = (gridDim.x * blockDim.x) >> 6;
    for (int e = wid; e < E; e += nw) {
        int s = src[e];
        int d = dst[e];
        int r = et[e];
        const float4* xr = reinterpret_cast<const float4*>(X + (size_t)s * F);
#pragma unroll
        for (int h = 0; h < 2; h++) {
            int fo = lane + (h << 6);
            const float4* wr = reinterpret_cast<const float4*>(W + ((size_t)r * F + fo) * F);
            float acc = 0.f;
#pragma unroll
            for (int i = 0; i < 32; i++) {
                float4 x = xr[i];
                float4 w = wr[i];
                acc += x.x * w.x + x.y * w.y + x.z * w.z + x.w * w.w;
            }
            unsafeAtomicAdd(&Y[(size_t)d * F + fo], acc);
        }
    }
}

extern "C" void kernel_launch(void* const* d_in, const int* in_sizes, int n_in,
                              void* d_out, int out_size, void* d_ws, size_t ws_size,
                              hipStream_t stream) {
    const float* X = (const float*)d_in[0];
    const float* W = (const float*)d_in[1];
    const int* src = (const int*)d_in[2];
    const int* dst = (const int*)d_in[3];
    const int* et  = (const int*)d_in[4];
    int N = in_sizes[0] / F;
    int E = in_sizes[2];
    float* Y = (float*)d_out;

    size_t x2bytes  = (size_t)N * F * 2;
    size_t w2bytes  = (size_t)RELS * F * F * 2;
    size_t cntbytes = ((size_t)N * 4 + 255) & ~255ull;
    size_t pkbytes  = (size_t)N * KMAX * 4;
    size_t need = x2bytes + w2bytes + cntbytes + pkbytes;

    if (ws_size < need) {
        hipMemsetAsync(d_out, 0, (size_t)N * F * sizeof(float), stream);
        fused_fb_kernel<<<2048, 256, 0, stream>>>(X, W, src, dst, et, Y, E);
        return;
    }

    char* ws = (char*)d_ws;
    unsigned short* X2 = (unsigned short*)ws;  ws += x2bytes;
    unsigned short* W2 = (unsigned short*)ws;  ws += w2bytes;
    int* counts        = (int*)ws;             ws += cntbytes;
    unsigned int* packed = (unsigned int*)ws;

    int BF = (E + 255) / 256;
    int BX = (N * (F / 8) + 255) / 256;
    int BW = (RELS * F * (F / 8) + 255) / 256;

    hipMemsetAsync(counts, 0, (size_t)N * 4, stream);
    prep_kernel<<<BF + BX + BW, 256, 0, stream>>>(X, W, src, dst, et, X2, W2, counts, packed, E, N, BF, BX);
    fused_kernel<<<(N + NT - 1) / NT, 256, 0, stream>>>((const unsigned int*)X2, W2, counts, packed, Y, N);
}